// Round 4
// baseline (125.063 us; speedup 1.0000x reference)
//
#include <hip/hip_runtime.h>
#include <hip/hip_cooperative_groups.h>

namespace cg = cooperative_groups;

#define NH 254
#define NSTEP 32
#define NB 256
#define NBLK 65   // 64 worker blocks + 1 solver block

constexpr float  FEPS = 1e-4f;
constexpr double DDT  = 1.0 / 60.0;
constexpr double DQV  = 200.0;
constexpr double DPQ  = 5.0;
constexpr double DQA  = 1.0;
constexpr double DEPS = 1e-4;

// ---------------------------------------------------------------------------
// One cooperative kernel, 65 blocks x 256 threads, 2 grid syncs.
//  A: blocks 0-63: partial t (4 rows each, 4 independent loads/thread),
//     Lq rows stashed in LDS, x fragment prefetched to registers.
//  B: all blocks reduce t (64 independent strided loads, unroll 16);
//     blocks 0-63: g rows from LDS; block 64: fp64 c -> Q_final -> GJ -> coef.
//  C: blocks 0-63: s_b = x_b.g from registers+LDS, write out.
// ---------------------------------------------------------------------------
__global__ __launch_bounds__(256) void k_all(const float* __restrict__ Lq,
                                             const float* __restrict__ Af,
                                             const float* __restrict__ x,
                                             const float* __restrict__ gp,
                                             const float* __restrict__ gv,
                                             float* __restrict__ ws,
                                             float* __restrict__ out) {
    float* partial = ws;              // 64*256 floats
    float* g       = ws + 64 * 256;   // 256 floats
    float* coef    = g + 256;         // 64 floats

    __shared__ float  lq_sh[4][256];
    __shared__ float  sh[256];        // t in phase B, g in phase C
    __shared__ double red[4];
    __shared__ double M[32][34];
    __shared__ double ua[32], ub[32];

    const int bid  = blockIdx.x;
    const int k    = threadIdx.x;
    const int lane = k & 63;
    const int w    = k >> 6;

    cg::grid_group grid = cg::this_grid();

    float xr[4] = {0.f, 0.f, 0.f, 0.f};
    float gpv = 0.f, gvv = 0.f;

    // ---------------- Phase A ----------------
    if (bid < 64) {
        // 4 independent Lq loads (rows 4*bid .. 4*bid+3, this thread's column k)
        float lqv[4];
        #pragma unroll
        for (int j = 0; j < 4; ++j) {
            const int i = 4 * bid + j;
            lqv[j] = (i < NH && k < NH) ? Lq[i * NH + k] : 0.f;
        }
        // prefetch phase-C operands (latency hides under phases A+B)
        const int r = 4 * bid + w;    // batch row for this wave, 0..255
        #pragma unroll
        for (int c4 = 0; c4 < 4; ++c4) {
            const int kk = lane + 64 * c4;
            xr[c4] = (kk < NH) ? x[r * NH + kk] : 0.f;
        }
        gpv = gp[r];
        gvv = gv[r];

        float acc = 0.f;
        #pragma unroll
        for (int j = 0; j < 4; ++j) {
            const int i = 4 * bid + j;
            const float afv = (i < NH) ? Af[i] : 0.f;   // broadcast load
            lq_sh[j][k] = lqv[j];
            acc += lqv[j] * afv;
        }
        partial[bid * 256 + k] = acc;
    }
    grid.sync();

    // ---------------- Phase B ----------------
    {
        float tk = 0.f;
        #pragma unroll 16
        for (int b = 0; b < 64; ++b) tk += partial[b * 256 + k];
        sh[k] = tk;                   // sh == t
    }
    __syncthreads();

    if (bid < 64) {
        // wave w -> g row i = 4*bid + w (Lq row already in LDS; upper triangle
        // is stored zeros, so no masking needed)
        const int i = 4 * bid + w;
        float a2 = 0.f;
        #pragma unroll
        for (int c4 = 0; c4 < 4; ++c4) {
            const int kk = lane + 64 * c4;
            a2 += lq_sh[w][kk] * sh[kk];
        }
        #pragma unroll
        for (int off = 32; off; off >>= 1) a2 += __shfl_xor(a2, off, 64);
        if (lane == 0 && i < NH) g[i] = a2 + FEPS * Af[i];
    } else {
        // ---- block 64: fp64 scalar pipeline ----
        double v = 0.0;
        if (k < NH) {
            const double td = (double)sh[k];
            const double ad = (double)Af[k];
            v = td * td + DEPS * ad * ad;
        }
        #pragma unroll
        for (int off = 32; off; off >>= 1) v += __shfl_xor(v, off, 64);
        if (lane == 0) red[w] = v;
        __syncthreads();
        const double c = red[0] + red[1] + red[2] + red[3];

        // Q_final entries: 1024 entries over 256 threads
        for (int e = k; e < 1024; e += 256) {
            const int j1 = e >> 5, j2 = e & 31;
            const int m = (j1 > j2) ? j1 : j2;
            double s = 0.0;
            for (int kk = m; kk < 32; ++kk) {
                const double wk = (kk == 31) ? DPQ : 1.0;
                s += wk * ((double)(kk - j1) * (double)(kk - j2) * c + DQV);
            }
            M[j1][j2] = 2.0 * DDT * DDT * s + ((j1 == j2) ? (2.0 * DQA + DEPS) : 0.0);
        }
        // RHS: alpha (col 32), beta (col 33)
        if (k < 32) {
            const int j = k;
            double sa = 0.0, sb = 0.0;
            for (int kk = j; kk < 32; ++kk) {
                const double wk = (kk == 31) ? DPQ : 1.0;
                sa += wk * (double)(kk - j);
                sb += wk * ((double)(kk + 1) * (double)(kk - j) * c + DQV);
            }
            M[j][32] = 2.0 * DDT * sa;
            M[j][33] = 2.0 * DDT * sb;
        }
        __syncthreads();

        // Gauss-Jordan, no pivoting (SPD). Thread -> (row r, col-group cg8).
        const int r   = k & 31;
        const int cg8 = k >> 5;   // 0..7
        for (int p = 0; p < 32; ++p) {
            const double f = M[r][p] / M[p][p];
            if (r != p) {
                for (int cc = cg8; cc < 34; cc += 8)
                    if (cc > p) M[r][cc] -= f * M[p][cc];
            }
            __syncthreads();
        }

        if (k < 32) {
            ua[k] = -M[k][32] / M[k][k];
            ub[k] = -M[k][33] / M[k][k];
        }
        __syncthreads();

        if (k < 32) {
            const int i = k;
            double ca = 0.0, cb = 0.0;
            for (int j = 0; j <= i; ++j) {
                const double wgt = (double)(i - j) + 0.5;
                ca += wgt * ua[j];
                cb += wgt * ub[j];
            }
            ca *= DDT * DDT;
            cb *= DDT * DDT;
            coef[i]      = (float)ca;                           // Calpha_i
            coef[32 + i] = (float)((double)(i + 1) * DDT + cb); // (i+1)dt + Cbeta_i
        }
    }
    __threadfence();
    grid.sync();

    // ---------------- Phase C ----------------
    if (bid < 64) {
        sh[k] = (k < NH) ? g[k] : 0.f;    // sh == g now
        __syncthreads();
        float s = 0.f;
        #pragma unroll
        for (int c4 = 0; c4 < 4; ++c4)
            s += xr[c4] * sh[lane + 64 * c4];
        #pragma unroll
        for (int off = 32; off; off >>= 1) s += __shfl_xor(s, off, 64);
        const int r = 4 * bid + w;
        if (lane < 32)
            out[r * NSTEP + lane] = gpv + gvv * coef[32 + lane] + s * coef[lane];
    }
}

extern "C" void kernel_launch(void* const* d_in, const int* in_sizes, int n_in,
                              void* d_out, int out_size, void* d_ws, size_t ws_size,
                              hipStream_t stream) {
    const float* x  = (const float*)d_in[0];   // [256,254]
    const float* gp = (const float*)d_in[1];   // [256]
    const float* gv = (const float*)d_in[2];   // [256]
    // d_in[3] (other_gripper_v) unused by the forward path
    const float* Af = (const float*)d_in[4];   // [254]
    const float* Lq = (const float*)d_in[5];   // [254,254]
    float* out = (float*)d_out;                // [256,32]
    float* ws  = (float*)d_ws;

    void* args[] = {(void*)&Lq, (void*)&Af, (void*)&x, (void*)&gp, (void*)&gv,
                    (void*)&ws, (void*)&out};
    hipLaunchCooperativeKernel((const void*)k_all, dim3(NBLK), dim3(256),
                               args, 0, stream);
}

// Round 6
// 93.159 us; speedup vs baseline: 1.3425x; 1.3425x over previous
//
#include <hip/hip_runtime.h>

#define NH 254
#define NSTEP 32
#define NB 256

constexpr float  FEPS = 1e-4f;
constexpr double DDT  = 1.0 / 60.0;
constexpr double DQV  = 200.0;
constexpr double DPQ  = 5.0;
constexpr double DQA  = 1.0;
constexpr double DEPS = 1e-4;

// ---------------------------------------------------------------------------
// ONE kernel, ONE block of 1024 threads (16 waves), zero workspace.
//  T: t = Lq^T Af     (thread (q,k): 64-row chunk q, col k; 8-deep load batches)
//  G: g = Lq t + eps Af (1 row/wave, 2-row interleave, L2-hot)
//  S: fp64 c -> Q_final -> Gauss-Jordan (2 RHS) -> coef   (proven pipeline)
//  O: out[b,i] = gp_b + gv_b*cB_i + (x_b . g)*cA_i  (2 rows/wave-iter)
// ---------------------------------------------------------------------------
__global__ __launch_bounds__(1024) void k_mono(const float* __restrict__ Lq,
                                               const float* __restrict__ Af,
                                               const float* __restrict__ x,
                                               const float* __restrict__ gp,
                                               const float* __restrict__ gv,
                                               float* __restrict__ out) {
    __shared__ float  af_sh[256];
    __shared__ float  tpart[4][256];
    __shared__ float  t_sh[256];
    __shared__ float  g_sh[256];
    __shared__ double red[4];
    __shared__ double M[32][34];
    __shared__ double ua[32], ub[32];
    __shared__ float  cA[32], cB[32];

    const int tid  = threadIdx.x;     // 0..1023
    const int k8   = tid & 255;
    const int q    = tid >> 8;        // 0..3
    const int lane = tid & 63;
    const int wv   = tid >> 6;        // 0..15

    if (q == 0) af_sh[k8] = (k8 < NH) ? Af[k8] : 0.f;
    if (tid == 0) { g_sh[254] = 0.f; g_sh[255] = 0.f; }
    __syncthreads();

    // ---------------- Phase T: tpart[q][k] = sum_{i in chunk q} Lq[i,k]*Af[i]
    {
        float acc = 0.f;
        const int ibase = q * 64;
        if (k8 < NH && k8 < ibase + 64) {   // skip chunks entirely above diagonal
            const int iend = (ibase + 64 < NH) ? ibase + 64 : NH;
            for (int i0 = ibase; i0 < iend; i0 += 8) {
                float v[8];
                #pragma unroll
                for (int j = 0; j < 8; ++j)
                    v[j] = (i0 + j < iend) ? Lq[(i0 + j) * NH + k8] : 0.f;
                #pragma unroll
                for (int j = 0; j < 8; ++j)
                    acc += v[j] * af_sh[i0 + j];   // af_sh index <= 255, safe
            }
        }
        tpart[q][k8] = acc;
    }
    __syncthreads();
    if (tid < 256)
        t_sh[tid] = tpart[0][tid] + tpart[1][tid] + tpart[2][tid] + tpart[3][tid];
    __syncthreads();

    // ---------------- Phase G: g_i = Lq[i,:] . t  + eps*Af_i  (rows i = wv+16r)
    for (int r = 0; r < 16; r += 2) {
        const int i1 = wv + 16 * r;        // <= 239, always valid
        const int i2 = i1 + 16;            // may be >= NH
        float lv1[4], lv2[4];
        #pragma unroll
        for (int c = 0; c < 4; ++c) {
            const int kk = lane + 64 * c;
            lv1[c] = (kk <= i1) ? Lq[i1 * NH + kk] : 0.f;
            lv2[c] = (i2 < NH && kk <= i2) ? Lq[i2 * NH + kk] : 0.f;
        }
        float a1 = 0.f, a2 = 0.f;
        #pragma unroll
        for (int c = 0; c < 4; ++c) {
            const int kk = lane + 64 * c;
            a1 += lv1[c] * t_sh[kk];
            a2 += lv2[c] * t_sh[kk];
        }
        #pragma unroll
        for (int off = 32; off; off >>= 1) {
            a1 += __shfl_xor(a1, off, 64);
            a2 += __shfl_xor(a2, off, 64);
        }
        if (lane == 0) {
            g_sh[i1] = a1 + FEPS * af_sh[i1];
            if (i2 < NH) g_sh[i2] = a2 + FEPS * af_sh[i2];
        }
    }
    __syncthreads();

    // ---------------- Phase S: fp64 scalar pipeline ----------------
    {
        double dv = 0.0;
        if (tid < NH) {
            const double td = (double)t_sh[tid];
            const double ad = (double)af_sh[tid];
            dv = td * td + DEPS * ad * ad;
        }
        #pragma unroll
        for (int off = 32; off; off >>= 1) dv += __shfl_xor(dv, off, 64);
        if (wv < 4 && lane == 0) red[wv] = dv;
    }
    __syncthreads();
    const double c = red[0] + red[1] + red[2] + red[3];

    // Q_final: one entry per thread
    {
        const int j1 = tid >> 5, j2 = tid & 31;
        const int m = (j1 > j2) ? j1 : j2;
        double s = 0.0;
        for (int kk = m; kk < 32; ++kk) {
            const double wk = (kk == 31) ? DPQ : 1.0;
            s += wk * ((double)(kk - j1) * (double)(kk - j2) * c + DQV);
        }
        M[j1][j2] = 2.0 * DDT * DDT * s + ((j1 == j2) ? (2.0 * DQA + DEPS) : 0.0);
    }
    // RHS: alpha (col 32), beta (col 33)
    if (tid < 32) {
        const int j = tid;
        double sa = 0.0, sb = 0.0;
        for (int kk = j; kk < 32; ++kk) {
            const double wk = (kk == 31) ? DPQ : 1.0;
            sa += wk * (double)(kk - j);
            sb += wk * ((double)(kk + 1) * (double)(kk - j) * c + DQV);
        }
        M[j][32] = 2.0 * DDT * sa;
        M[j][33] = 2.0 * DDT * sb;
    }
    __syncthreads();

    // Gauss-Jordan, no pivoting (SPD). Thread -> (row r, cols {cg, cg+32}).
    {
        const int r  = tid & 31;
        const int cg = tid >> 5;     // 0..31
        for (int p = 0; p < 32; ++p) {
            const double f = M[r][p] / M[p][p];
            if (r != p) {
                if (cg > p) M[r][cg] -= f * M[p][cg];
                const int c2 = cg + 32;
                if (c2 < 34) M[r][c2] -= f * M[p][c2];   // c2 > p always
            }
            __syncthreads();
        }
    }
    if (tid < 32) {
        ua[tid] = -M[tid][32] / M[tid][tid];
        ub[tid] = -M[tid][33] / M[tid][tid];
    }
    __syncthreads();
    if (tid < 32) {
        const int i = tid;
        double ca = 0.0, cb = 0.0;
        for (int j = 0; j <= i; ++j) {
            const double wgt = (double)(i - j) + 0.5;
            ca += wgt * ua[j];
            cb += wgt * ub[j];
        }
        cA[i] = (float)(ca * DDT * DDT);                           // Calpha_i
        cB[i] = (float)((double)(i + 1) * DDT + cb * DDT * DDT);   // (i+1)dt + Cbeta_i
    }
    __syncthreads();

    // ---------------- Phase O: output, 2 batch rows per wave-iteration
    for (int r = 0; r < 16; r += 2) {
        const int b1 = wv + 16 * r;        // 0..255
        const int b2 = b1 + 16;            // 0..255 (256 = 16 waves * 16 rows)
        float xa[4], xb[4];
        #pragma unroll
        for (int cidx = 0; cidx < 4; ++cidx) {
            const int kk = lane + 64 * cidx;
            xa[cidx] = (kk < NH) ? x[b1 * NH + kk] : 0.f;
            xb[cidx] = (kk < NH) ? x[b2 * NH + kk] : 0.f;
        }
        float s1 = 0.f, s2 = 0.f;
        #pragma unroll
        for (int cidx = 0; cidx < 4; ++cidx) {
            const int kk = lane + 64 * cidx;
            s1 += xa[cidx] * g_sh[kk];
            s2 += xb[cidx] * g_sh[kk];
        }
        #pragma unroll
        for (int off = 32; off; off >>= 1) {
            s1 += __shfl_xor(s1, off, 64);
            s2 += __shfl_xor(s2, off, 64);
        }
        if (lane < 32) {
            out[b1 * NSTEP + lane] = gp[b1] + gv[b1] * cB[lane] + s1 * cA[lane];
            out[b2 * NSTEP + lane] = gp[b2] + gv[b2] * cB[lane] + s2 * cA[lane];
        }
    }
}

extern "C" void kernel_launch(void* const* d_in, const int* in_sizes, int n_in,
                              void* d_out, int out_size, void* d_ws, size_t ws_size,
                              hipStream_t stream) {
    const float* x  = (const float*)d_in[0];   // [256,254]
    const float* gp = (const float*)d_in[1];   // [256]
    const float* gv = (const float*)d_in[2];   // [256]
    // d_in[3] (other_gripper_v) unused by the forward path
    const float* Af = (const float*)d_in[4];   // [254]
    const float* Lq = (const float*)d_in[5];   // [254,254]
    float* out = (float*)d_out;                // [256,32]

    k_mono<<<1, 1024, 0, stream>>>(Lq, Af, x, gp, gv, out);
}